// Round 6
// baseline (1787.758 us; speedup 1.0000x reference)
//
#include <hip/hip_runtime.h>
#include <hip/hip_bf16.h>

// TriangleSelfAttention — fp32 baseline, v3.
// v2 ran without crashing (ws-cap + mask-detect held) but failed absmax=4.76:
// gemm_out staged only 512 of 2048 float4 B-slots (p<2 instead of p<8), so
// Bs rows 16..63 were garbage. v3 fixes that single loop bound.
// B=1, I=J=384, E=128, H=4, C=32, AHS=128. N = I*J = 147456 rows.
//
// Pipeline:
//   1. mask_zero/mask_detect : flag = (mask is 1-byte bool)
//   2. fused_ln_qkvg         : LN(z) @ [Wqkv|Wg]; q,k,v -> ws, sigmoid(g) -> d_out
//   3. attn_kernel           : per (i,h) softmax(QK^T*scale)V * g -> over q-slice
//   4. gemm_out              : (g*attn) @ Wo + bo, * z_mask -> d_out
//
// The reference's softmax bias is constant along the key axis (mask indexes
// the query axis) -> shift-invariance makes it a no-op. Skipped.

#define TSA_I   384
#define TSA_J   384
#define TSA_N   (TSA_I * TSA_J)      // 147456
#define TSA_SCALE 0.17677669529663687f  // 1/sqrt(32)

// ---------------------------------------------------------------- mask detect
__global__ __launch_bounds__(64) void mask_zero(int* flag) {
    if (threadIdx.x == 0) *flag = 0;
}
__global__ __launch_bounds__(256) void mask_detect(const unsigned char* __restrict__ m,
                                                   int* __restrict__ flag) {
    int i = blockIdx.x * 256 + threadIdx.x;
    if (i < TSA_N && (i & 3) && m[i]) atomicOr(flag, 1);
}

// ---------------------------------------------------------------- LN + GEMM qkvg
// rows: BM=32/block. cols: all 512 (q 0..383 -> ws, g 384..511 -> sigmoid -> gbuf).
// BK=16, 256 threads, thread tile 4x16. LDS ~51.5 KB -> 3 blocks/CU.
__global__ __launch_bounds__(256) void fused_ln_qkvg(const float* __restrict__ z,
                                                     const float* __restrict__ ln_g,
                                                     const float* __restrict__ ln_b,
                                                     const float* __restrict__ Wqkv,
                                                     const float* __restrict__ Wg,
                                                     const float* __restrict__ bg,
                                                     float* __restrict__ qkv,
                                                     float* __restrict__ gbuf) {
    __shared__ float As[128][36];    // normalized A^T: As[k][m]
    __shared__ float Bs[16][516];    // Bs[kk][n]
    const int tid  = threadIdx.x;
    const int row0 = blockIdx.x * 32;

    // ---- phase 1: load z rows, layernorm, write As (transposed)
    {
        const int lrow = tid >> 3;           // 0..31
        const int sub  = tid & 7;            // 0..7 (same wave within a row)
        float vals[16];
        const float* zp = z + (size_t)(row0 + lrow) * 128 + sub * 16;
#pragma unroll
        for (int j = 0; j < 4; ++j)
            *(float4*)(vals + j * 4) = *(const float4*)(zp + j * 4);
        float s = 0.f;
#pragma unroll
        for (int j = 0; j < 16; ++j) s += vals[j];
        s += __shfl_xor(s, 1); s += __shfl_xor(s, 2); s += __shfl_xor(s, 4);
        const float mu = s * (1.f / 128.f);
        float vs = 0.f;
#pragma unroll
        for (int j = 0; j < 16; ++j) { float d = vals[j] - mu; vs += d * d; }
        vs += __shfl_xor(vs, 1); vs += __shfl_xor(vs, 2); vs += __shfl_xor(vs, 4);
        const float rstd = rsqrtf(vs * (1.f / 128.f) + 1e-5f);
        float gg[16], bb[16];
#pragma unroll
        for (int j = 0; j < 4; ++j) {
            *(float4*)(gg + j * 4) = *(const float4*)(ln_g + sub * 16 + j * 4);
            *(float4*)(bb + j * 4) = *(const float4*)(ln_b + sub * 16 + j * 4);
        }
#pragma unroll
        for (int j = 0; j < 16; ++j)
            As[sub * 16 + j][lrow] = (vals[j] - mu) * rstd * gg[j] + bb[j];
    }
    __syncthreads();

    // ---- phase 2: GEMM over K in chunks of 16
    const int tm = (tid & 7) * 4;            // 0..28
    const int tn = (tid >> 3) * 16;          // 0..496 (16-aligned: no 384-straddle)
    float acc[4][16] = {};
    for (int k0 = 0; k0 < 128; k0 += 16) {
#pragma unroll
        for (int p = 0; p < 8; ++p) {
            int flat = tid + 256 * p;        // 0..2047 float4 slots (16 x 128)
            int kk = flat >> 7, c4 = flat & 127;
            int col = c4 * 4, k = k0 + kk;
            float4 w;
            if (col < 384) w = *(const float4*)(Wqkv + (size_t)k * 384 + col);
            else           w = *(const float4*)(Wg   + (size_t)k * 128 + (col - 384));
            *(float4*)(&Bs[kk][col]) = w;
        }
        __syncthreads();
#pragma unroll
        for (int kk = 0; kk < 16; ++kk) {
            float a[4], b[16];
            *(float4*)a = *(const float4*)(&As[k0 + kk][tm]);
#pragma unroll
            for (int v4 = 0; v4 < 4; ++v4)
                *(float4*)(b + v4 * 4) = *(const float4*)(&Bs[kk][tn + v4 * 4]);
#pragma unroll
            for (int u = 0; u < 4; ++u)
#pragma unroll
                for (int v = 0; v < 16; ++v) acc[u][v] += a[u] * b[v];
        }
        __syncthreads();
    }

    // ---- epilogue
    if (tn < 384) {
#pragma unroll
        for (int u = 0; u < 4; ++u) {
            int row = row0 + tm + u;
#pragma unroll
            for (int v4 = 0; v4 < 4; ++v4)
                *(float4*)(qkv + (size_t)row * 384 + tn + v4 * 4) = *(float4*)(&acc[u][v4 * 4]);
        }
    } else {
        const int c0 = tn - 384;             // 0..112
        float bgl[16];
#pragma unroll
        for (int v4 = 0; v4 < 4; ++v4)
            *(float4*)(bgl + v4 * 4) = *(const float4*)(bg + c0 + v4 * 4);
#pragma unroll
        for (int u = 0; u < 4; ++u) {
            int row = row0 + tm + u;
            float tmp[16];
#pragma unroll
            for (int v = 0; v < 16; ++v)
                tmp[v] = 1.f / (1.f + __expf(-(acc[u][v] + bgl[v])));
#pragma unroll
            for (int v4 = 0; v4 < 4; ++v4)
                *(float4*)(gbuf + (size_t)row * 128 + c0 + v4 * 4) = *(float4*)(tmp + v4 * 4);
        }
    }
}

// ---------------------------------------------------------------- attention
// block = (i, h); 384 threads = one lane per q-row. K,V staged fp32 in LDS (96 KB).
// Online softmax (deferred rescale, exact math). Writes g*attn over the q-slice.
__global__ __launch_bounds__(384) void attn_kernel(float* __restrict__ qkv,
                                                   const float* __restrict__ gbuf) {
    const int i = blockIdx.x >> 2, h = blockIdx.x & 3;
    __shared__ float Ks[TSA_J * 32];
    __shared__ float Vs[TSA_J * 32];
    const int tid = threadIdx.x;
    const size_t base = (size_t)i * TSA_J * 384;
#pragma unroll
    for (int p = 0; p < 8; ++p) {
        int f = tid + 384 * p;               // 0..3071 float4 slots
        int j = f >> 3, c4 = f & 7;
        const float* kp = qkv + base + (size_t)j * 384 + 128 + h * 32 + c4 * 4;
        const float* vp = qkv + base + (size_t)j * 384 + 256 + h * 32 + c4 * 4;
        *(float4*)(&Ks[j * 32 + c4 * 4]) = *(const float4*)kp;
        *(float4*)(&Vs[j * 32 + c4 * 4]) = *(const float4*)vp;
    }

    const int qr = tid;                      // 0..383
    const float* qp = qkv + base + (size_t)qr * 384 + h * 32;
    float q[32];
#pragma unroll
    for (int c4 = 0; c4 < 8; ++c4)
        *(float4*)(q + c4 * 4) = *(const float4*)(qp + c4 * 4);
    __syncthreads();

    float acc[32] = {};
    float mrun = -1e30f, l = 0.f;
    for (int k = 0; k < TSA_J; ++k) {
        const float* kr = &Ks[k * 32];
        float s0 = 0.f, s1 = 0.f, s2 = 0.f, s3 = 0.f;
#pragma unroll
        for (int c = 0; c < 8; ++c) {
            s0 += q[c]      * kr[c];
            s1 += q[c + 8]  * kr[c + 8];
            s2 += q[c + 16] * kr[c + 16];
            s3 += q[c + 24] * kr[c + 24];
        }
        float s = ((s0 + s1) + (s2 + s3)) * TSA_SCALE;
        if (s > mrun + 3.f) {                // deferred rescale (rare)
            float corr = __expf(mrun - s);
            l *= corr;
#pragma unroll
            for (int c = 0; c < 32; ++c) acc[c] *= corr;
            mrun = s;
        }
        float w = __expf(s - mrun);
        l += w;
        const float* vr = &Vs[k * 32];
#pragma unroll
        for (int c = 0; c < 32; ++c) acc[c] += w * vr[c];
    }
    const float inv = 1.f / l;
    const float* gp = gbuf + ((size_t)i * TSA_J + qr) * 128 + h * 32;
    float* op = qkv + base + (size_t)qr * 384 + h * 32;   // over own q-slice
#pragma unroll
    for (int c4 = 0; c4 < 8; ++c4) {
        float4 g4 = *(const float4*)(gp + c4 * 4);
        float4 o4;
        o4.x = acc[c4 * 4 + 0] * inv * g4.x;
        o4.y = acc[c4 * 4 + 1] * inv * g4.y;
        o4.z = acc[c4 * 4 + 2] * inv * g4.z;
        o4.w = acc[c4 * 4 + 3] * inv * g4.w;
        *(float4*)(op + c4 * 4) = o4;
    }
}

// ---------------------------------------------------------------- GEMM out
// out[N,128] = (GA[N,128] @ Wo[128,128] + bo) * mask[row]; GA = qkv q-slice (lda 384).
__global__ __launch_bounds__(256) void gemm_out(const float* __restrict__ A,
                                                const float* __restrict__ W,
                                                const float* __restrict__ bo,
                                                const void* __restrict__ zmask,
                                                const int* __restrict__ flag,
                                                float* __restrict__ out) {
    __shared__ float As[64][68];
    __shared__ float Bs[64][132];
    const int tid  = threadIdx.x;
    const int row0 = blockIdx.x * 64;
    const int tmi = tid & 15, tni = tid >> 4;
    const int tm0 = tmi * 4, tn0 = tni * 8;
    float acc[4][8] = {};
    for (int k0 = 0; k0 < 128; k0 += 64) {
        {
            int m = tid & 63, f = tid >> 6;
            const float* ap = A + (size_t)(row0 + m) * 384 + k0 + f * 16;
#pragma unroll
            for (int j = 0; j < 4; ++j) {
                float4 v = *(const float4*)(ap + j * 4);
                int kk = f * 16 + j * 4;
                As[kk + 0][m] = v.x; As[kk + 1][m] = v.y;
                As[kk + 2][m] = v.z; As[kk + 3][m] = v.w;
            }
        }
        {
            // 64 rows x 32 float4-cols = 2048 slots -> p<8 with 256 threads.
            // (v2 had p<2 here: Bs rows 16..63 were never staged -> absmax 4.76)
#pragma unroll
            for (int p = 0; p < 8; ++p) {
                int flat = tid + 256 * p;    // 0..2047 float4 slots (64 x 32)
                int kk = flat >> 5, c4 = flat & 31;
                float4 v = *(const float4*)(W + (size_t)(k0 + kk) * 128 + c4 * 4);
                *(float4*)(&Bs[kk][c4 * 4]) = v;
            }
        }
        __syncthreads();
#pragma unroll
        for (int kk = 0; kk < 64; ++kk) {
            float a[4], b[8];
            *(float4*)a       = *(const float4*)(&As[kk][tm0]);
            *(float4*)(b)     = *(const float4*)(&Bs[kk][tn0]);
            *(float4*)(b + 4) = *(const float4*)(&Bs[kk][tn0 + 4]);
#pragma unroll
            for (int u = 0; u < 4; ++u)
#pragma unroll
                for (int v = 0; v < 8; ++v) acc[u][v] += a[u] * b[v];
        }
        __syncthreads();
    }
    const int fl = *flag;
#pragma unroll
    for (int u = 0; u < 4; ++u) {
        int row = row0 + tm0 + u;
        int mi;
        if (fl) mi = ((const unsigned char*)zmask)[row];     // 1-byte bool
        else    mi = ((const int*)zmask)[row];               // int32
        float mv = (mi != 0) ? 1.f : 0.f;
        float tmp[8];
#pragma unroll
        for (int v = 0; v < 8; ++v)
            tmp[v] = (acc[u][v] + bo[tn0 + v]) * mv;
        *(float4*)(out + (size_t)row * 128 + tn0)     = *(float4*)tmp;
        *(float4*)(out + (size_t)row * 128 + tn0 + 4) = *(float4*)(tmp + 4);
    }
}

// ---------------------------------------------------------------- launch
extern "C" void kernel_launch(void* const* d_in, const int* in_sizes, int n_in,
                              void* d_out, int out_size, void* d_ws, size_t ws_size,
                              hipStream_t stream) {
    const float* z    = (const float*)d_in[0];
    const void*  zm   = d_in[1];
    const float* ln_g = (const float*)d_in[2];
    const float* ln_b = (const float*)d_in[3];
    const float* Wqkv = (const float*)d_in[4];
    const float* Wg   = (const float*)d_in[5];
    const float* bg   = (const float*)d_in[6];
    const float* Wo   = (const float*)d_in[7];
    const float* bo   = (const float*)d_in[8];
    float* out = (float*)d_out;

    const size_t qkv_bytes = (size_t)TSA_N * 384 * 4;    // 226,492,416
    if (ws_size < qkv_bytes + 64) return;                // fail cleanly, don't fault

    float* qkv  = (float*)d_ws;
    int*   flag = (int*)((char*)d_ws + qkv_bytes);

    mask_zero<<<1, 64, 0, stream>>>(flag);
    mask_detect<<<TSA_N / 256, 256, 0, stream>>>((const unsigned char*)zm, flag);
    fused_ln_qkvg<<<TSA_N / 32, 256, 0, stream>>>(z, ln_g, ln_b, Wqkv, Wg, bg,
                                                  qkv, out /* g scratch */);
    attn_kernel<<<TSA_I * 4, 384, 0, stream>>>(qkv, out /* g */);
    gemm_out<<<TSA_N / 64, 256, 0, stream>>>(qkv /* g*attn, lda 384 */, Wo, bo,
                                             zm, flag, out);
}

// Round 12
// 751.979 us; speedup vs baseline: 2.3774x; 2.3774x over previous
//
#include <hip/hip_runtime.h>
#include <hip/hip_bf16.h>
#include <hip/hip_fp16.h>

// TriangleSelfAttention — v4b: f16 MFMA GEMMs + f16 dot2 attention.
// (Resubmit: rounds 9-11 all failed before execution — broker timeouts and
// a container failure; v4b has never run on hardware.)
// v4 failed to COMPILE (11 errors): (a) cvt_pkrtz returns __fp16-vec,
// incompatible with _Float16-vec in assignment -> replaced with scalar
// (_Float16) casts; (b) shufflevector needs constant indices -> replaced
// H2AT macro with union h8/h2 access. No functional/layout changes vs v4.
// B=1, I=J=384, E=128, H=4, C=32. N = 147456.
// v3 (fp32 baseline) passed: 1788 us, absmax 9.8e-4, threshold 1.07e-2.
//   attn 1106 us (VALU-bound, occ 14.7%), gemms ~680 us.

typedef _Float16 h2 __attribute__((ext_vector_type(2)));
typedef _Float16 h8 __attribute__((ext_vector_type(8)));
typedef float f32x4 __attribute__((ext_vector_type(4)));

union H8u { h8 v; h2 h[4]; };

#define TSA_I 384
#define TSA_J 384
#define TSA_N (TSA_I * TSA_J)
#define TSA_SCALE 0.17677669529663687f
#define MFMA16(a, b, c) __builtin_amdgcn_mfma_f32_16x16x32_f16((a), (b), (c), 0, 0, 0)

// ---------------------------------------------------------------- mask detect
__global__ __launch_bounds__(64) void mask_zero(int* flag) {
    if (threadIdx.x == 0) *flag = 0;
}
__global__ __launch_bounds__(256) void mask_detect(const unsigned char* __restrict__ m,
                                                   int* __restrict__ flag) {
    int i = blockIdx.x * 256 + threadIdx.x;
    if (i < TSA_N && (i & 3) && m[i]) atomicOr(flag, 1);
}

// ---------------------------------------------------------------- pack weights
// WT[col][k] = [Wqkv | Wg]^T in f16 (512x128); WoT[col][k] = Wo^T f16 (128x128).
__global__ __launch_bounds__(256) void pack_w(const float* __restrict__ Wqkv,
                                              const float* __restrict__ Wg,
                                              const float* __restrict__ Wo,
                                              _Float16* __restrict__ WT,
                                              _Float16* __restrict__ WoT) {
    int idx = blockIdx.x * 256 + threadIdx.x;
    if (idx < 512 * 128) {
        int col = idx >> 7, k = idx & 127;
        float w = (col < 384) ? Wqkv[k * 384 + col] : Wg[k * 128 + (col - 384)];
        WT[idx] = (_Float16)w;
    } else if (idx < 512 * 128 + 128 * 128) {
        int j = idx - 512 * 128;
        int col = j >> 7, k = j & 127;
        WoT[j] = (_Float16)Wo[k * 128 + col];
    }
}

// ---------------------------------------------------------------- LN + QKV/G GEMM (MFMA)
// grid (N/64, 4 colgroups of 128), 256 thr = 4 waves (2M x 2N), wave tile 32x64.
__global__ __launch_bounds__(256) void ln_qkvg_mfma(const float* __restrict__ z,
                                                    const float* __restrict__ ln_g,
                                                    const float* __restrict__ ln_b,
                                                    const _Float16* __restrict__ WT,
                                                    const float* __restrict__ bg,
                                                    _Float16* __restrict__ qkv,
                                                    _Float16* __restrict__ gbuf) {
    __shared__ _Float16 As[64][136];     // [row][k] f16, padded stride (272B, 16B-aligned)
    const int tid  = threadIdx.x;
    const int row0 = blockIdx.x * 64;
    const int cg   = blockIdx.y;         // column group: cols cg*128 .. +127

    // ---- LN: 4 threads/row, 32 f32 each
    {
        const int r = tid >> 2, sub = tid & 3;
        const float* zp = z + (size_t)(row0 + r) * 128 + sub * 32;
        float v[32];
#pragma unroll
        for (int j = 0; j < 8; ++j) *(float4*)(v + 4 * j) = *(const float4*)(zp + 4 * j);
        float s = 0.f;
#pragma unroll
        for (int j = 0; j < 32; ++j) s += v[j];
        s += __shfl_xor(s, 1); s += __shfl_xor(s, 2);
        const float mu = s * (1.f / 128.f);
        float vs = 0.f;
#pragma unroll
        for (int j = 0; j < 32; ++j) { float d = v[j] - mu; vs += d * d; }
        vs += __shfl_xor(vs, 1); vs += __shfl_xor(vs, 2);
        const float rstd = rsqrtf(vs * (1.f / 128.f) + 1e-5f);
#pragma unroll
        for (int j4 = 0; j4 < 8; ++j4) {
            float4 gg = *(const float4*)(ln_g + sub * 32 + j4 * 4);
            float4 bb = *(const float4*)(ln_b + sub * 32 + j4 * 4);
            float n0 = (v[j4 * 4 + 0] - mu) * rstd * gg.x + bb.x;
            float n1 = (v[j4 * 4 + 1] - mu) * rstd * gg.y + bb.y;
            float n2 = (v[j4 * 4 + 2] - mu) * rstd * gg.z + bb.z;
            float n3 = (v[j4 * 4 + 3] - mu) * rstd * gg.w + bb.w;
            h2 p0, p1;
            p0[0] = (_Float16)n0; p0[1] = (_Float16)n1;
            p1[0] = (_Float16)n2; p1[1] = (_Float16)n3;
            *(h2*)(&As[r][sub * 32 + j4 * 4])     = p0;
            *(h2*)(&As[r][sub * 32 + j4 * 4 + 2]) = p1;
        }
    }
    __syncthreads();

    // ---- MFMA: K=128 in 4 steps of 32
    const int wave = tid >> 6, lane = tid & 63;
    const int wm = wave >> 1, wn = wave & 1;
    const int l15 = lane & 15, lg = lane >> 4;
    f32x4 acc[2][4] = {};
    const _Float16* wbase = WT + (size_t)(cg * 128 + wn * 64 + l15) * 128 + lg * 8;
    const _Float16* abase = &As[wm * 32 + l15][lg * 8];
#pragma unroll
    for (int ks = 0; ks < 4; ++ks) {
        h8 a0 = *(const h8*)(abase + ks * 32);
        h8 a1 = *(const h8*)(abase + 16 * 136 + ks * 32);
#pragma unroll
        for (int nt = 0; nt < 4; ++nt) {
            h8 b = *(const h8*)(wbase + nt * 16 * 128 + ks * 32);
            acc[0][nt] = MFMA16(a0, b, acc[0][nt]);
            acc[1][nt] = MFMA16(a1, b, acc[1][nt]);
        }
    }

    // ---- epilogue: cols<384 -> qkv f16; cols>=384 -> sigmoid -> gbuf f16
#pragma unroll
    for (int mt = 0; mt < 2; ++mt) {
#pragma unroll
        for (int nt = 0; nt < 4; ++nt) {
            const int gcol = cg * 128 + wn * 64 + nt * 16 + l15;
#pragma unroll
            for (int r = 0; r < 4; ++r) {
                const int grow = row0 + wm * 32 + mt * 16 + lg * 4 + r;
                const float val = acc[mt][nt][r];
                if (gcol < 384) {
                    qkv[(size_t)grow * 384 + gcol] = (_Float16)val;
                } else {
                    float x = val + bg[gcol - 384];
                    float sg = 1.f / (1.f + __expf(-x));
                    gbuf[(size_t)grow * 128 + (gcol - 384)] = (_Float16)sg;
                }
            }
        }
    }
}

// ---------------------------------------------------------------- attention (f16 dot2)
// block = (i,h), 384 thr = one lane per q-row. K[384][32] + V^T[32][384] f16 in LDS.
// Online softmax (deferred rescale, exact), k processed in chunks of 8.
__global__ __launch_bounds__(384) void attn_f16(_Float16* __restrict__ qkv,
                                                const _Float16* __restrict__ gbuf) {
    const int i = blockIdx.x >> 2, h = blockIdx.x & 3;
    __shared__ _Float16 Ks[384][32];
    __shared__ _Float16 VTs[32][384];
    const int t = threadIdx.x;
    const size_t rowg = (size_t)i * 384 + t;
    const _Float16* qp = qkv + rowg * 384 + h * 32;
    const _Float16* kp = qkv + rowg * 384 + 128 + h * 32;
    const _Float16* vp = qkv + rowg * 384 + 256 + h * 32;
    H8u qv[4];
    h8 kv[4], vv[4];
#pragma unroll
    for (int j = 0; j < 4; ++j) {
        qv[j].v = *(const h8*)(qp + 8 * j);
        kv[j]   = *(const h8*)(kp + 8 * j);
        vv[j]   = *(const h8*)(vp + 8 * j);
    }
#pragma unroll
    for (int j = 0; j < 4; ++j) *(h8*)(&Ks[t][8 * j]) = kv[j];
#pragma unroll
    for (int c = 0; c < 32; ++c) VTs[c][t] = vv[c >> 3][c & 7];   // per-c: 64 contig lanes
    __syncthreads();

    float acc[32] = {};
    float mrun = -1e30f, l = 0.f;
    for (int kc = 0; kc < 384; kc += 8) {
        float sarr[8];
#pragma unroll
        for (int j = 0; j < 8; ++j) {
            const h8* krp = (const h8*)(&Ks[kc + j][0]);
            H8u k0, k1, k2, k3;
            k0.v = krp[0]; k1.v = krp[1]; k2.v = krp[2]; k3.v = krp[3];
            float s0 = 0.f, s1 = 0.f, s2 = 0.f, s3 = 0.f;
#pragma unroll
            for (int p = 0; p < 4; ++p) {
                s0 = __builtin_amdgcn_fdot2(qv[0].h[p], k0.h[p], s0, false);
                s1 = __builtin_amdgcn_fdot2(qv[1].h[p], k1.h[p], s1, false);
                s2 = __builtin_amdgcn_fdot2(qv[2].h[p], k2.h[p], s2, false);
                s3 = __builtin_amdgcn_fdot2(qv[3].h[p], k3.h[p], s3, false);
            }
            sarr[j] = ((s0 + s1) + (s2 + s3)) * TSA_SCALE;
        }
        const float m8 = fmaxf(fmaxf(fmaxf(sarr[0], sarr[1]), fmaxf(sarr[2], sarr[3])),
                               fmaxf(fmaxf(sarr[4], sarr[5]), fmaxf(sarr[6], sarr[7])));
        if (m8 > mrun + 3.f) {               // deferred rescale (rare; exact math)
            const float corr = __expf(mrun - m8);
            l *= corr;
#pragma unroll
            for (int c = 0; c < 32; ++c) acc[c] *= corr;
            mrun = m8;
        }
        h2 w2[4];
        float lsum = 0.f;
#pragma unroll
        for (int p = 0; p < 4; ++p) {
            const float wa = __expf(sarr[2 * p]     - mrun);
            const float wb = __expf(sarr[2 * p + 1] - mrun);
            lsum += wa + wb;
            w2[p][0] = (_Float16)wa;
            w2[p][1] = (_Float16)wb;
        }
        l += lsum;
#pragma unroll
        for (int c = 0; c < 32; ++c) {
            H8u vt;
            vt.v = *(const h8*)(&VTs[c][kc]);
            float a = acc[c];
            a = __builtin_amdgcn_fdot2(w2[0], vt.h[0], a, false);
            a = __builtin_amdgcn_fdot2(w2[1], vt.h[1], a, false);
            a = __builtin_amdgcn_fdot2(w2[2], vt.h[2], a, false);
            a = __builtin_amdgcn_fdot2(w2[3], vt.h[3], a, false);
            acc[c] = a;
        }
    }
    const float inv = 1.f / l;
    const _Float16* gp = gbuf + rowg * 128 + h * 32;
    _Float16* op = qkv + rowg * 384 + h * 32;     // overwrite own q-slice (race-free)
#pragma unroll
    for (int c = 0; c < 32; ++c)
        op[c] = (_Float16)(acc[c] * inv * (float)gp[c]);
}

// ---------------------------------------------------------------- out GEMM (MFMA, LDS-free)
// out[N,128] = (ga[N,128] @ Wo + bo) * mask. ga = qkv q-slice f16 (lda 384).
__global__ __launch_bounds__(256) void gemm_out_mfma(const _Float16* __restrict__ ga,
                                                     const _Float16* __restrict__ WoT,
                                                     const float* __restrict__ bo,
                                                     const void* __restrict__ zmask,
                                                     const int* __restrict__ flag,
                                                     float* __restrict__ out) {
    const int tid  = threadIdx.x;
    const int row0 = blockIdx.x * 64;
    const int wave = tid >> 6, lane = tid & 63;
    const int wm = wave >> 1, wn = wave & 1;
    const int l15 = lane & 15, lg = lane >> 4;
    f32x4 acc[2][4] = {};
    const _Float16* ab = ga + (size_t)(row0 + wm * 32 + l15) * 384 + lg * 8;
    const _Float16* bb = WoT + (size_t)(wn * 64 + l15) * 128 + lg * 8;
#pragma unroll
    for (int ks = 0; ks < 4; ++ks) {
        h8 a0 = *(const h8*)(ab + ks * 32);
        h8 a1 = *(const h8*)(ab + (size_t)16 * 384 + ks * 32);
#pragma unroll
        for (int nt = 0; nt < 4; ++nt) {
            h8 b = *(const h8*)(bb + nt * 16 * 128 + ks * 32);
            acc[0][nt] = MFMA16(a0, b, acc[0][nt]);
            acc[1][nt] = MFMA16(a1, b, acc[1][nt]);
        }
    }
    const int fl = *flag;
#pragma unroll
    for (int mt = 0; mt < 2; ++mt) {
#pragma unroll
        for (int nt = 0; nt < 4; ++nt) {
            const int gcol = wn * 64 + nt * 16 + l15;
#pragma unroll
            for (int r = 0; r < 4; ++r) {
                const int grow = row0 + wm * 32 + mt * 16 + lg * 4 + r;
                int mi;
                if (fl) mi = ((const unsigned char*)zmask)[grow];
                else    mi = ((const int*)zmask)[grow];
                const float mv = (mi != 0) ? 1.f : 0.f;
                out[(size_t)grow * 128 + gcol] = (acc[mt][nt][r] + bo[gcol]) * mv;
            }
        }
    }
}

// ---------------------------------------------------------------- launch
extern "C" void kernel_launch(void* const* d_in, const int* in_sizes, int n_in,
                              void* d_out, int out_size, void* d_ws, size_t ws_size,
                              hipStream_t stream) {
    const float* z    = (const float*)d_in[0];
    const void*  zm   = d_in[1];
    const float* ln_g = (const float*)d_in[2];
    const float* ln_b = (const float*)d_in[3];
    const float* Wqkv = (const float*)d_in[4];
    const float* Wg   = (const float*)d_in[5];
    const float* bg   = (const float*)d_in[6];
    const float* Wo   = (const float*)d_in[7];
    const float* bo   = (const float*)d_in[8];
    float* out = (float*)d_out;

    const size_t qkv_bytes = (size_t)TSA_N * 384 * 2;   // 113,246,208
    const size_t wt_bytes  = 512 * 128 * 2;
    const size_t wot_bytes = 128 * 128 * 2;
    if (ws_size < qkv_bytes + wt_bytes + wot_bytes + 64) return;

    _Float16* qkv  = (_Float16*)d_ws;
    _Float16* WT   = (_Float16*)((char*)d_ws + qkv_bytes);
    _Float16* WoT  = WT + 512 * 128;
    int*      flag = (int*)((char*)d_ws + qkv_bytes + wt_bytes + wot_bytes);
    _Float16* gbuf = (_Float16*)d_out;   // g parked in d_out (f16), consumed by attn

    mask_zero<<<1, 64, 0, stream>>>(flag);
    mask_detect<<<TSA_N / 256, 256, 0, stream>>>((const unsigned char*)zm, flag);
    pack_w<<<320, 256, 0, stream>>>(Wqkv, Wg, Wo, WT, WoT);
    ln_qkvg_mfma<<<dim3(TSA_N / 64, 4), 256, 0, stream>>>(z, ln_g, ln_b, WT, bg, qkv, gbuf);
    attn_f16<<<TSA_I * 4, 384, 0, stream>>>(qkv, gbuf);
    gemm_out_mfma<<<TSA_N / 64, 256, 0, stream>>>(qkv, WoT, bo, zm, flag, out);
}